// Round 10
// baseline (271.201 us; speedup 1.0000x reference)
//
#include <hip/hip_runtime.h>
#include <hip/hip_bf16.h>

#define SEQ   512
#define BATCH 128
#define FEAT  1024
#define EMBED 1024
#define NLANG 8

typedef __attribute__((ext_vector_type(8))) short bf16x8;
typedef __attribute__((ext_vector_type(4))) float f32x4;
typedef unsigned short ushort_t;

__device__ __forceinline__ unsigned pk2(float a, float b) {
  float2 f; f.x = a; f.y = b;
  __hip_bfloat162 h = __float22bfloat162_rn(f);   // v_cvt_pk_bf16_f32
  union { __hip_bfloat162 h2; unsigned u; } cv;
  cv.h2 = h;
  return cv.u;
}

__device__ __forceinline__ void gld16(const void* g, void* l) {
  __builtin_amdgcn_global_load_lds(
      (const __attribute__((address_space(1))) void*)g,
      (__attribute__((address_space(3))) void*)l, 16, 0, 0);
}

// ---------------- Pass 1: f32->bf16 convert; feat rows permuted into language
// buckets (row p = segbase[tok] + s*cnt[tok] + rank[b]); W converted linear.
// (R4-verified; ~77 us, near BW floor.) ---------------------------------------
__global__ __launch_bounds__(256) void convert_permute_kernel(
    const float* __restrict__ feat,   // [S*B, F]
    const float* __restrict__ Wf,     // [L*E*F]
    const int*   __restrict__ toks,   // [B]
    ushort_t* __restrict__ Abf,       // [S*B, F] permuted
    ushort_t* __restrict__ Wbf)       // [L*E*F]
{
  __shared__ int stok[128];
  __shared__ int srank[128];
  __shared__ int scnt[8];
  __shared__ int sbase[8];

  const int tid = threadIdx.x;
  if (tid < 128) stok[tid] = toks[tid];
  __syncthreads();
  if (tid < 128) {
    int myt = stok[tid], r = 0;
    for (int j = 0; j < 128; ++j) r += (j < tid) && (stok[j] == myt);
    srank[tid] = r;
  }
  if (tid < 8) {
    int c = 0;
    for (int j = 0; j < 128; ++j) c += (stok[j] == tid);
    scnt[tid] = c;
  }
  __syncthreads();
  if (tid < 8) {
    int b = 0;
    for (int j = 0; j < tid; ++j) b += scnt[j];
    sbase[tid] = b << 9;
  }
  __syncthreads();

  const int FC = (SEQ * BATCH * FEAT) / 4;
  const int TC = FC + (NLANG * EMBED * FEAT) / 4;
  for (int c = blockIdx.x * 256 + tid; c < TC; c += gridDim.x * 256) {
    if (c < FC) {
      float4 v = ((const float4*)feat)[c];
      const int r = c >> 8, q = c & 255;
      const int b = r & 127, s = r >> 7;
      const int tk = stok[b];
      const int p = sbase[tk] + s * scnt[tk] + srank[b];
      uint2 o; o.x = pk2(v.x, v.y); o.y = pk2(v.z, v.w);
      *(uint2*)(Abf + ((size_t)p << 10) + (q << 2)) = o;
    } else {
      const int c2 = c - FC;
      float4 v = ((const float4*)Wf)[c2];
      uint2 o; o.x = pk2(v.x, v.y); o.y = pk2(v.z, v.w);
      *(uint2*)(Wbf + ((size_t)c2 << 2)) = o;
    }
  }
}

// ---------------- Pass 2: pipelined 256x256 grouped GEMM, 16 WAVES ---------
// (R4's verified structure redistributed to 1024 threads for 4 waves/SIMD.)
// BK=32 granules, ring-4 LDS (4 x (16+16) KiB = 128 KiB), counted vmcnt(4),
// raw barriers, R4-verified XOR swizzle, setprio. 16 waves = 4M x 4N; each
// wave computes 64x64 via acc[4][4] of mfma_f32_16x16x32_bf16.
__global__ __launch_bounds__(1024) void grouped_gemm_w16(
    const ushort_t* __restrict__ Abf,  // [S*B, F] bucket-permuted bf16
    const ushort_t* __restrict__ Wbf,  // [L, E, F] bf16
    const float* __restrict__ bias,    // [L, E]
    const int*   __restrict__ toks,    // [B]
    float*       __restrict__ out)     // [S*B, E] original order
{
  extern __shared__ ushort_t lds[];          // 65536 ushort = 128 KiB
  __shared__ int tokarr[128];
  __shared__ unsigned long long ballots[2][8];
  __shared__ int perm[128];
  __shared__ int rowsrc[256];

  const int tid = threadIdx.x;
  const int l   = tid & 63;
  const int w   = tid >> 6;                  // 0..15
  const int wr  = w >> 2;                    // 0..3 (M quarter)
  const int wc  = w & 3;                     // 0..3 (N quarter)

  // XCD-chunked bijective swizzle (1024 blocks = 8 XCDs x 128).
  const int bid = blockIdx.x;
  const int L   = (bid & 7) * 128 + (bid >> 3);
  const int et  = L & 3;
  const int mt  = (L >> 7) * 32 + ((L >> 2) & 31);
  const int m0  = mt * 256;
  const int e0  = et * 256;

  // ---- bucket setup (ballot histogram + rank; waves 0,1 vote) ----
  if (tid < 128) tokarr[tid] = toks[tid];
  __syncthreads();
  if (tid < 128) {
    int myt = tokarr[tid];
#pragma unroll
    for (int lg = 0; lg < 8; ++lg) {
      unsigned long long bl = __ballot(myt == lg);
      if (l == 0) ballots[w][lg] = bl;
    }
  }
  __syncthreads();

  int lsel = 0, base = 0, csel = 1, boff_sel = 0;
  {
    int cum = 0, boff = 0;
#pragma unroll
    for (int lg = 0; lg < 8; ++lg) {
      int c = __popcll(ballots[0][lg]) + __popcll(ballots[1][lg]);
      int seg = c << 9;
      bool in = (m0 >= cum) && (m0 < cum + seg);
      if (in) { lsel = lg; base = cum; csel = c; boff_sel = boff; }
      cum += seg; boff += c;
    }
  }

  if (tid < 128) {
    int myt = tokarr[tid];
    unsigned long long ltm = (1ull << l) - 1ull;
    int rank = (w == 0) ? __popcll(ballots[0][myt] & ltm)
                        : __popcll(ballots[0][myt]) + __popcll(ballots[1][myt] & ltm);
    int boff2 = 0;
#pragma unroll
    for (int lg = 0; lg < 8; ++lg) {
      int c = __popcll(ballots[0][lg]) + __popcll(ballots[1][lg]);
      boff2 += (lg < myt) ? c : 0;
    }
    perm[boff2 + rank] = tid;
  }
  __syncthreads();
  if (tid < 256) {
    int local = m0 - base + tid;
    int s = local / csel;
    int j = local - s * csel;
    rowsrc[tid] = s * BATCH + perm[boff_sel + j];
  }
  __syncthreads();

  // ---- staging: granule = 256 rows x 32 bf16 = 16 KiB = 1024 chunks of
  // 16B; chunk c = row*4 + cc; wave w owns chunks w*64 + l (lane-seq dest,
  // wave-uniform base). Source k-chunk = cc ^ ((row>>1)&3) (R4-verified). ----
  const int ch  = w * 64 + l;
  const int rw  = ch >> 2;
  const int cc  = ch & 3;
  const int sK  = (rw >> 1) & 3;
  const ushort_t* aS = Abf + (size_t)(m0 + rw) * FEAT + ((cc ^ sK) * 8);
  const ushort_t* bS = Wbf + ((size_t)lsel * EMBED + e0 + rw) * FEAT + ((cc ^ sK) * 8);
  const int dOff = w * 512;                  // ushort units within a buf

  // ---- fragment read offsets (R4-verified family; XOR key invariant
  // across the +16-row fragment steps) ----
  const int kc  = l >> 4;
  const int rA  = wr * 64 + (l & 15);
  const int aRd = rA * 32 + ((kc ^ ((rA >> 1) & 3)) * 8);
  const int rB  = wc * 64 + (l & 15);
  const int bRd = rB * 32 + ((kc ^ ((rB >> 1) & 3)) * 8);

  f32x4 acc[4][4] = {};

#define STAGE(kt, buf)                                                     \
  do {                                                                     \
    const int _o = (kt) * 32;                                              \
    gld16(aS + _o, lds + (buf) * 8192 + dOff);                             \
    gld16(bS + _o, lds + 32768 + (buf) * 8192 + dOff);                     \
  } while (0)

  // prologue: stage K-granules 0,1,2 (6 loads); vmcnt(4) -> granule 0
  // resident (in-order retire leaves granules 1,2 = 4 outstanding).
  STAGE(0, 0);
  STAGE(1, 1);
  STAGE(2, 2);
  asm volatile("s_waitcnt vmcnt(4)" ::: "memory");
  __builtin_amdgcn_s_barrier();
  __builtin_amdgcn_sched_barrier(0);

  const int NT = FEAT / 32;                   // 32 granules
  for (int t = 0; t < NT; ++t) {
    const ushort_t* Ab = lds + (t & 3) * 8192;
    const ushort_t* Bb = lds + 32768 + (t & 3) * 8192;
    if (t < NT - 3) STAGE(t + 3, (t + 3) & 3);

    bf16x8 af[4], bfq[4];
#pragma unroll
    for (int mf = 0; mf < 4; ++mf)
      af[mf] = *(const bf16x8*)(Ab + aRd + mf * 512);
#pragma unroll
    for (int nf = 0; nf < 4; ++nf)
      bfq[nf] = *(const bf16x8*)(Bb + bRd + nf * 512);

    __builtin_amdgcn_s_setprio(1);
#pragma unroll
    for (int mf = 0; mf < 4; ++mf)
#pragma unroll
      for (int nf = 0; nf < 4; ++nf)
        acc[mf][nf] = __builtin_amdgcn_mfma_f32_16x16x32_bf16(
            af[mf], bfq[nf], acc[mf][nf], 0, 0, 0);
    __builtin_amdgcn_s_setprio(0);

    // counted waits (2 loads/granule): steady vmcnt(4) retires granule t+1.
    if (t < NT - 3)       asm volatile("s_waitcnt vmcnt(4)" ::: "memory");
    else if (t == NT - 3) asm volatile("s_waitcnt vmcnt(2)" ::: "memory");
    else if (t == NT - 2) asm volatile("s_waitcnt vmcnt(0)" ::: "memory");
    if (t < NT - 1) {
      __builtin_amdgcn_s_barrier();
      __builtin_amdgcn_sched_barrier(0);
    }
  }
#undef STAGE

  // ---- epilogue: C/D col = lane&15 (-> e), row = (lane>>4)*4+j (-> m) ----
  const int col = l & 15;
  const int r4  = (l >> 4) * 4;
  float bvv[4];
#pragma unroll
  for (int nf = 0; nf < 4; ++nf)
    bvv[nf] = bias[lsel * EMBED + e0 + wc * 64 + nf * 16 + col];
#pragma unroll
  for (int mf = 0; mf < 4; ++mf) {
#pragma unroll
    for (int j = 0; j < 4; ++j) {
      const size_t ro = (size_t)rowsrc[wr * 64 + mf * 16 + r4 + j] * EMBED;
#pragma unroll
      for (int nf = 0; nf < 4; ++nf)
        out[ro + e0 + wc * 64 + nf * 16 + col] = acc[mf][nf][j] + bvv[nf];
    }
  }
}

// ---------------- Fallback (R2 fused kernel) if ws too small ----------------
__global__ __launch_bounds__(256, 2) void grouped_proj_fused(
    const float* __restrict__ feat, const float* __restrict__ Wt,
    const float* __restrict__ bias, const int* __restrict__ toks,
    float* __restrict__ out)
{
  __shared__ uint4 As[1024];
  __shared__ uint4 Bs[1024];
  __shared__ int tokarr[128];
  __shared__ unsigned long long ballots[2][8];
  __shared__ int perm[128];
  __shared__ int rowsrc[128];

  const int tid  = threadIdx.x;
  const int lane = tid & 63;
  const int wv   = tid >> 6;
  const int wr   = wv >> 1;
  const int wc   = wv & 1;
  const int bid = blockIdx.x;
  const int xcd = bid & 7;
  const int sq  = bid >> 3;
  const int et  = sq & 7;
  const int mt  = (sq >> 3) * 8 + xcd;
  const int m0  = mt * 128;
  const int e0  = et * 128;

  if (tid < 128) tokarr[tid] = toks[tid];
  __syncthreads();
  if (tid < 128) {
    int myt = tokarr[tid];
#pragma unroll
    for (int lg = 0; lg < 8; ++lg) {
      unsigned long long bl = __ballot(myt == lg);
      if (lane == 0) ballots[wv][lg] = bl;
    }
  }
  __syncthreads();
  int lsel = 0, base = 0, csel = 1, boff_sel = 0;
  {
    int cum = 0, boff = 0;
#pragma unroll
    for (int lg = 0; lg < 8; ++lg) {
      int c = __popcll(ballots[0][lg]) + __popcll(ballots[1][lg]);
      int seg = c << 9;
      bool in = (m0 >= cum) && (m0 < cum + seg);
      if (in) { lsel = lg; base = cum; csel = c; boff_sel = boff; }
      cum += seg; boff += c;
    }
  }
  if (tid < 128) {
    int myt = tokarr[tid];
    unsigned long long ltm = (1ull << lane) - 1ull;
    int rank = (wv == 0) ? __popcll(ballots[0][myt] & ltm)
                         : __popcll(ballots[0][myt]) + __popcll(ballots[1][myt] & ltm);
    int boff2 = 0;
#pragma unroll
    for (int lg = 0; lg < 8; ++lg) {
      int c = __popcll(ballots[0][lg]) + __popcll(ballots[1][lg]);
      boff2 += (lg < myt) ? c : 0;
    }
    perm[boff2 + rank] = tid;
  }
  __syncthreads();
  if (tid < 128) {
    int local = m0 - base + tid;
    int s = local / csel;
    int j = local - s * csel;
    rowsrc[tid] = s * BATCH + perm[boff_sel + j];
  }
  __syncthreads();

  int slot_i[4];
  const float* aptr[4];
  const float* bptr[4];
#pragma unroll
  for (int it = 0; it < 4; ++it) {
    int c    = it * 256 + tid;
    int kg   = c & 7;
    int row  = c >> 3;
    int ksub = kg & 3;
    int kk   = kg >> 2;
    int frag = row >> 4;
    slot_i[it] = (kk * 8 + frag) * 64 + ((row & 15) ^ (ksub << 1) ^ kk) + ksub * 16;
    aptr[it] = feat + (size_t)rowsrc[row] * FEAT + kg * 8;
    bptr[it] = Wt + ((size_t)lsel * EMBED + e0 + row) * FEAT + kg * 8;
  }

  f32x4 acc[4][4] = {};
  for (int k0 = 0; k0 < FEAT; k0 += 64) {
    __syncthreads();
#pragma unroll
    for (int it = 0; it < 4; ++it) {
      float4 alo = *(const float4*)(aptr[it] + k0);
      float4 ahi = *(const float4*)(aptr[it] + k0 + 4);
      uint4 av;
      av.x = pk2(alo.x, alo.y); av.y = pk2(alo.z, alo.w);
      av.z = pk2(ahi.x, ahi.y); av.w = pk2(ahi.z, ahi.w);
      As[slot_i[it]] = av;
      float4 blo = *(const float4*)(bptr[it] + k0);
      float4 bhi = *(const float4*)(bptr[it] + k0 + 4);
      uint4 bv;
      bv.x = pk2(blo.x, blo.y); bv.y = pk2(blo.z, blo.w);
      bv.z = pk2(bhi.x, bhi.y); bv.w = pk2(bhi.z, bhi.w);
      Bs[slot_i[it]] = bv;
    }
    __syncthreads();
#pragma unroll
    for (int kk = 0; kk < 2; ++kk) {
      const int ksr = lane >> 4;
      const int sw  = ((lane & 15) ^ (ksr << 1) ^ kk) + ksr * 16;
      bf16x8 af[4], bfr[4];
#pragma unroll
      for (int mi = 0; mi < 4; ++mi)
        af[mi] = ((const bf16x8*)As)[(kk * 8 + wr * 4 + mi) * 64 + sw];
#pragma unroll
      for (int ni = 0; ni < 4; ++ni)
        bfr[ni] = ((const bf16x8*)Bs)[(kk * 8 + wc * 4 + ni) * 64 + sw];
#pragma unroll
      for (int mi = 0; mi < 4; ++mi)
#pragma unroll
        for (int ni = 0; ni < 4; ++ni)
          acc[mi][ni] = __builtin_amdgcn_mfma_f32_16x16x32_bf16(
              af[mi], bfr[ni], acc[mi][ni], 0, 0, 0);
    }
  }

  const int col = lane & 15;
  const int r0  = (lane >> 4) * 4;
  float bvv[4];
#pragma unroll
  for (int ni = 0; ni < 4; ++ni)
    bvv[ni] = bias[lsel * EMBED + e0 + wc * 64 + ni * 16 + col];
#pragma unroll
  for (int mi = 0; mi < 4; ++mi) {
#pragma unroll
    for (int j = 0; j < 4; ++j) {
      const size_t ro = (size_t)rowsrc[wr * 64 + mi * 16 + r0 + j] * EMBED;
#pragma unroll
      for (int ni = 0; ni < 4; ++ni)
        out[ro + e0 + wc * 64 + ni * 16 + col] = acc[mi][ni][j] + bvv[ni];
    }
  }
}

extern "C" void kernel_launch(void* const* d_in, const int* in_sizes, int n_in,
                              void* d_out, int out_size, void* d_ws, size_t ws_size,
                              hipStream_t stream) {
  const float* feat = (const float*)d_in[0];
  const float* W    = (const float*)d_in[1];
  const float* bias = (const float*)d_in[2];
  const int*   toks = (const int*)d_in[3];
  float* out = (float*)d_out;

  const size_t abf_bytes = (size_t)SEQ * BATCH * FEAT * 2;        // 128 MiB
  const size_t wbf_bytes = (size_t)NLANG * EMBED * FEAT * 2;      // 16 MiB

  if (ws_size >= abf_bytes + wbf_bytes) {
    ushort_t* Abf = (ushort_t*)d_ws;
    ushort_t* Wbf = (ushort_t*)((char*)d_ws + abf_bytes);
    convert_permute_kernel<<<3072, 256, 0, stream>>>(feat, W, toks, Abf, Wbf);
    (void)hipFuncSetAttribute((const void*)grouped_gemm_w16,
                              hipFuncAttributeMaxDynamicSharedMemorySize, 131072);
    const int nblk = (SEQ * BATCH / 256) * (EMBED / 256);         // 1024
    grouped_gemm_w16<<<nblk, 1024, 131072, stream>>>(Abf, Wbf, bias, toks, out);
  } else {
    grouped_proj_fused<<<(SEQ * BATCH / 128) * (EMBED / 128), 256, 0, stream>>>(
        feat, W, bias, toks, out);
  }
}

// Round 11
// 257.267 us; speedup vs baseline: 1.0542x; 1.0542x over previous
//
#include <hip/hip_runtime.h>
#include <hip/hip_bf16.h>

#define SEQ   512
#define BATCH 128
#define FEAT  1024
#define EMBED 1024
#define NLANG 8

typedef __attribute__((ext_vector_type(8))) short bf16x8;
typedef __attribute__((ext_vector_type(4))) float f32x4;
typedef unsigned short ushort_t;

__device__ __forceinline__ unsigned pk2(float a, float b) {
  float2 f; f.x = a; f.y = b;
  __hip_bfloat162 h = __float22bfloat162_rn(f);   // v_cvt_pk_bf16_f32
  union { __hip_bfloat162 h2; unsigned u; } cv;
  cv.h2 = h;
  return cv.u;
}

__device__ __forceinline__ bf16x8 cvt8(float4 lo, float4 hi) {
  union { bf16x8 v; unsigned u[4]; } q;
  q.u[0] = pk2(lo.x, lo.y); q.u[1] = pk2(lo.z, lo.w);
  q.u[2] = pk2(hi.x, hi.y); q.u[3] = pk2(hi.z, hi.w);
  return q.v;
}

__device__ __forceinline__ void gld16(const void* g, void* l) {
  __builtin_amdgcn_global_load_lds(
      (const __attribute__((address_space(1))) void*)g,
      (__attribute__((address_space(3))) void*)l, 16, 0, 0);
}

// ---------------- Pass 1 (W only): f32 -> bf16, linear. ~48 MB traffic. -----
__global__ __launch_bounds__(256) void convert_w_kernel(
    const float* __restrict__ Wf, ushort_t* __restrict__ Wbf)
{
  const int n = (NLANG * EMBED * FEAT) / 4;
  for (int c = blockIdx.x * 256 + threadIdx.x; c < n; c += gridDim.x * 256) {
    float4 v = ((const float4*)Wf)[c];
    uint2 o; o.x = pk2(v.x, v.y); o.y = pk2(v.z, v.w);
    *(uint2*)(Wbf + ((size_t)c << 2)) = o;
  }
}

// ---------------- Pass 2: fused grouped GEMM, 128x256 tile, 2 blocks/CU ----
// A: f32 feat rows gathered to regs (8 f32/thread/granule), cvt once,
// ds_write_b128 into R4-verified clean bf16 layout, ring-3 (24 KiB).
// B: bf16 gld16 ring-3 (48 KiB; R10-verified). 8 waves (2M x 4N), wave =
// 64x64 via acc[4][4]. 72 KiB LDS + <=128 VGPR -> 2 blocks/CU = 4 waves/SIMD
// with two INDEPENDENT barrier groups (one block fills the other's stalls).
// Wait ledger (order-robust): WRITE_A(t+1) at body top (cvt implicit-waits
// A(t+1), leaves B(t+1)+newer in flight); end-of-body vmcnt(4) retires
// exactly B(t+1); lgkmcnt(0) drains ds_writes before the barrier.
__global__ __launch_bounds__(512, 4) void grouped_gemm_fused(
    const float* __restrict__ feat,    // [S*B, F] f32 (original order)
    const ushort_t* __restrict__ Wbf,  // [L, E, F] bf16
    const float* __restrict__ bias,    // [L, E]
    const int*   __restrict__ toks,    // [B]
    float*       __restrict__ out)     // [S*B, E] original order
{
  extern __shared__ char ldsraw[];                 // 73728 B dynamic
  ushort_t* Alds = (ushort_t*)ldsraw;              // 3 bufs x 4096 us (8 KiB)
  ushort_t* Blds = (ushort_t*)(ldsraw + 24576);    // 3 bufs x 8192 us (16 KiB)
  __shared__ int tokarr[128];
  __shared__ unsigned long long ballots[2][8];
  __shared__ int perm[128];
  __shared__ int rowsrc[128];

  const int tid = threadIdx.x;
  const int l   = tid & 63;
  const int w   = tid >> 6;
  const int wr  = w >> 2;                    // 0..1 (M half of 128)
  const int wc  = w & 3;                     // 0..3 (N quarter of 256)

  // XCD-chunked bijective swizzle (2048 blocks = 8 XCDs x 256); the 4
  // et-siblings of one mt adjacent on one XCD (A-panel L2 reuse).
  const int bid = blockIdx.x;
  const int L   = (bid & 7) * 256 + (bid >> 3);
  const int et  = L & 3;
  const int mt  = L >> 2;                    // 0..511
  const int m0  = mt * 128;
  const int e0  = et * 256;

  // ---- bucket setup (ballot histogram + rank; waves 0,1 vote) ----
  if (tid < 128) tokarr[tid] = toks[tid];
  __syncthreads();
  if (tid < 128) {
    int myt = tokarr[tid];
#pragma unroll
    for (int lg = 0; lg < 8; ++lg) {
      unsigned long long bl = __ballot(myt == lg);
      if (l == 0) ballots[w][lg] = bl;
    }
  }
  __syncthreads();

  int lsel = 0, base = 0, csel = 1, boff_sel = 0;
  {
    int cum = 0, boff = 0;
#pragma unroll
    for (int lg = 0; lg < 8; ++lg) {
      int c = __popcll(ballots[0][lg]) + __popcll(ballots[1][lg]);
      int seg = c << 9;
      bool in = (m0 >= cum) && (m0 < cum + seg);
      if (in) { lsel = lg; base = cum; csel = c; boff_sel = boff; }
      cum += seg; boff += c;
    }
  }

  if (tid < 128) {
    int myt = tokarr[tid];
    unsigned long long ltm = (1ull << l) - 1ull;
    int rank = (w == 0) ? __popcll(ballots[0][myt] & ltm)
                        : __popcll(ballots[0][myt]) + __popcll(ballots[1][myt] & ltm);
    int boff2 = 0;
#pragma unroll
    for (int lg = 0; lg < 8; ++lg) {
      int c = __popcll(ballots[0][lg]) + __popcll(ballots[1][lg]);
      boff2 += (lg < myt) ? c : 0;
    }
    perm[boff2 + rank] = tid;
  }
  __syncthreads();
  if (tid < 128) {
    int local = m0 - base + tid;
    int s = local / csel;
    int j = local - s * csel;
    rowsrc[tid] = s * BATCH + perm[boff_sel + j];
  }
  __syncthreads();

  // ---- A reg-staging: granule = 128 rows x 32 f32. Thread owns row=tid>>2,
  // quarter aq=tid&3 (8 f32 = 32B, row segments 128B x 4 lanes coalesced).
  // cvt -> 1 bf16x8 chunk at LDS chunk arow*4 + (aq ^ ((arow>>1)&3))
  // (R4-verified clean family for both write and read phases). ----
  const int arow = tid >> 2;
  const int aq   = tid & 2 ? (tid & 3) : (tid & 3);  // = tid & 3
  const float* aSrcP = feat + (size_t)rowsrc[arow] * FEAT + (tid & 3) * 8;
  const int wchunk = arow * 4 + ((tid & 3) ^ ((arow >> 1) & 3));
  float4 ar0, ar1;                            // single in-flight A reg set
  (void)aq;

  // ---- B staging (R10-verified): granule = 256 erows x 32 bf16 = 1024
  // chunks; wave w owns chunks w*128+l and +64; src chunk = cc^((row>>1)&3).
  const int ch  = w * 128 + l;
  const int rwB = ch >> 2;
  const int ccB = ch & 3;
  const int sB  = (rwB >> 1) & 3;
  const ushort_t* bS0 = Wbf + ((size_t)lsel * EMBED + e0 + rwB) * FEAT + ((ccB ^ sB) * 8);
  const ushort_t* bS1 = bS0 + (size_t)16 * FEAT;
  const int bD0 = (w * 128) * 8;              // ushort units within a B buf
  const int bD1 = (w * 128 + 64) * 8;

  // ---- fragment read offsets (R4-verified family) ----
  const int kc  = l >> 4;
  const int rA  = wr * 64 + (l & 15);
  const int aRd = rA * 32 + ((kc ^ ((rA >> 1) & 3)) * 8);   // < 4096
  const int rB  = wc * 64 + (l & 15);
  const int bRd = rB * 32 + ((kc ^ ((rB >> 1) & 3)) * 8);   // < 8192

  f32x4 acc[4][4] = {};

#define LOAD_A(kt)                                                         \
  do { const float* _p = aSrcP + (kt) * 32;                                \
    ar0 = *(const float4*)(_p); ar1 = *(const float4*)(_p + 4); } while (0)
#define WRITE_A(buf)                                                       \
  do { ((bf16x8*)(Alds + (buf) * 4096))[wchunk] = cvt8(ar0, ar1); } while (0)
#define STAGE_B(kt, buf)                                                   \
  do { const int _o = (kt) * 32;                                           \
    gld16(bS0 + _o, Blds + (buf) * 8192 + bD0);                            \
    gld16(bS1 + _o, Blds + (buf) * 8192 + bD1); } while (0)

// Body t (J = t%3 compile-time). Steady: WRITE_A(t+1 -> buf (J+1)%3) at TOP
// (cvt implicit-waits A(t+1) regs loaded body t-1 -> full-granule depth);
// LOAD_A(t+2) + STAGE_B(t+2 -> buf (J+2)%3); frag reads buf J; 16 MFMA;
// end: vmcnt(4) retires exactly B(t+1) (robust to intra-body issue order),
// lgkmcnt(0) drains the ds_write, barrier.
#define BODY(t, J, DOWRITE, DOLOAD, ENDWAIT, ENDBAR)                       \
  do {                                                                     \
    if (DOWRITE) { WRITE_A(((J) + 1) % 3); }                               \
    if (DOLOAD)  { LOAD_A((t) + 2); STAGE_B((t) + 2, ((J) + 2) % 3); }     \
    const ushort_t* Ar_ = Alds + (J) * 4096;                               \
    const ushort_t* Br_ = Blds + (J) * 8192;                               \
    bf16x8 af[4], bfq[4];                                                  \
    _Pragma("unroll") for (int mf = 0; mf < 4; ++mf)                       \
        af[mf] = *(const bf16x8*)(Ar_ + aRd + mf * 512);                   \
    _Pragma("unroll") for (int nf = 0; nf < 4; ++nf)                       \
        bfq[nf] = *(const bf16x8*)(Br_ + bRd + nf * 512);                  \
    __builtin_amdgcn_s_setprio(1);                                         \
    _Pragma("unroll") for (int mf = 0; mf < 4; ++mf)                       \
        _Pragma("unroll") for (int nf = 0; nf < 4; ++nf)                   \
            acc[mf][nf] = __builtin_amdgcn_mfma_f32_16x16x32_bf16(         \
                af[mf], bfq[nf], acc[mf][nf], 0, 0, 0);                    \
    __builtin_amdgcn_s_setprio(0);                                         \
    asm volatile(ENDWAIT ::: "memory");                                    \
    if (ENDBAR) { __builtin_amdgcn_s_barrier();                            \
                  __builtin_amdgcn_sched_barrier(0); }                     \
  } while (0)

  // ---- prologue: A(0) -> regs -> cvt -> buf0; B(0),B(1) staged; A(1) -> regs.
  // vmcnt(4) retires B(0) (leaves B(1)x2 + A(1)x2); lgkm drains A(0) write.
  LOAD_A(0);
  WRITE_A(0);
  STAGE_B(0, 0);
  STAGE_B(1, 1);
  LOAD_A(1);
  asm volatile("s_waitcnt vmcnt(4) lgkmcnt(0)" ::: "memory");
  __builtin_amdgcn_s_barrier();
  __builtin_amdgcn_sched_barrier(0);

  // ---- main: bodies 0..29 (period-3 unroll) ----
#pragma unroll 1
  for (int gg = 0; gg < 10; ++gg) {
    const int g = gg * 3;
    BODY(g + 0, 0, true, true, "s_waitcnt vmcnt(4) lgkmcnt(0)", true);
    BODY(g + 1, 1, true, true, "s_waitcnt vmcnt(4) lgkmcnt(0)", true);
    BODY(g + 2, 2, true, true, "s_waitcnt vmcnt(4) lgkmcnt(0)", true);
  }
  // tails: body 30 (J=0): write A(31)->buf1, no loads; drain all B.
  BODY(30, 0, true, false, "s_waitcnt vmcnt(0) lgkmcnt(0)", true);
  // body 31 (J=1): compute only.
  BODY(31, 1, false, false, "s_nop 0", false);

#undef BODY
#undef LOAD_A
#undef WRITE_A
#undef STAGE_B

  // ---- epilogue: C/D col = lane&15 (-> e), row = (lane>>4)*4+j (-> m) ----
  const int col = l & 15;
  const int r4  = (l >> 4) * 4;
  float bvv[4];
#pragma unroll
  for (int nf = 0; nf < 4; ++nf)
    bvv[nf] = bias[lsel * EMBED + e0 + wc * 64 + nf * 16 + col];
#pragma unroll
  for (int mf = 0; mf < 4; ++mf) {
#pragma unroll
    for (int j = 0; j < 4; ++j) {
      const size_t ro = (size_t)rowsrc[wr * 64 + mf * 16 + r4 + j] * EMBED;
#pragma unroll
      for (int nf = 0; nf < 4; ++nf)
        out[ro + e0 + wc * 64 + nf * 16 + col] = acc[mf][nf][j] + bvv[nf];
    }
  }
}

// ---------------- Fallback (R2 fused kernel) if ws too small ----------------
__global__ __launch_bounds__(256, 2) void grouped_proj_fused(
    const float* __restrict__ feat, const float* __restrict__ Wt,
    const float* __restrict__ bias, const int* __restrict__ toks,
    float* __restrict__ out)
{
  __shared__ uint4 As[1024];
  __shared__ uint4 Bs[1024];
  __shared__ int tokarr[128];
  __shared__ unsigned long long ballots[2][8];
  __shared__ int perm[128];
  __shared__ int rowsrc[128];

  const int tid  = threadIdx.x;
  const int lane = tid & 63;
  const int wv   = tid >> 6;
  const int wr   = wv >> 1;
  const int wc   = wv & 1;
  const int bid = blockIdx.x;
  const int xcd = bid & 7;
  const int sq  = bid >> 3;
  const int et  = sq & 7;
  const int mt  = (sq >> 3) * 8 + xcd;
  const int m0  = mt * 128;
  const int e0  = et * 128;

  if (tid < 128) tokarr[tid] = toks[tid];
  __syncthreads();
  if (tid < 128) {
    int myt = tokarr[tid];
#pragma unroll
    for (int lg = 0; lg < 8; ++lg) {
      unsigned long long bl = __ballot(myt == lg);
      if (lane == 0) ballots[wv][lg] = bl;
    }
  }
  __syncthreads();
  int lsel = 0, base = 0, csel = 1, boff_sel = 0;
  {
    int cum = 0, boff = 0;
#pragma unroll
    for (int lg = 0; lg < 8; ++lg) {
      int c = __popcll(ballots[0][lg]) + __popcll(ballots[1][lg]);
      int seg = c << 9;
      bool in = (m0 >= cum) && (m0 < cum + seg);
      if (in) { lsel = lg; base = cum; csel = c; boff_sel = boff; }
      cum += seg; boff += c;
    }
  }
  if (tid < 128) {
    int myt = tokarr[tid];
    unsigned long long ltm = (1ull << lane) - 1ull;
    int rank = (wv == 0) ? __popcll(ballots[0][myt] & ltm)
                         : __popcll(ballots[0][myt]) + __popcll(ballots[1][myt] & ltm);
    int boff2 = 0;
#pragma unroll
    for (int lg = 0; lg < 8; ++lg) {
      int c = __popcll(ballots[0][lg]) + __popcll(ballots[1][lg]);
      boff2 += (lg < myt) ? c : 0;
    }
    perm[boff2 + rank] = tid;
  }
  __syncthreads();
  if (tid < 128) {
    int local = m0 - base + tid;
    int s = local / csel;
    int j = local - s * csel;
    rowsrc[tid] = s * BATCH + perm[boff_sel + j];
  }
  __syncthreads();

  int slot_i[4];
  const float* aptr[4];
  const float* bptr[4];
#pragma unroll
  for (int it = 0; it < 4; ++it) {
    int c    = it * 256 + tid;
    int kg   = c & 7;
    int row  = c >> 3;
    int ksub = kg & 3;
    int kk   = kg >> 2;
    int frag = row >> 4;
    slot_i[it] = (kk * 8 + frag) * 64 + ((row & 15) ^ (ksub << 1) ^ kk) + ksub * 16;
    aptr[it] = feat + (size_t)rowsrc[row] * FEAT + kg * 8;
    bptr[it] = Wt + ((size_t)lsel * EMBED + e0 + row) * FEAT + kg * 8;
  }

  f32x4 acc[4][4] = {};
  for (int k0 = 0; k0 < FEAT; k0 += 64) {
    __syncthreads();
#pragma unroll
    for (int it = 0; it < 4; ++it) {
      float4 alo = *(const float4*)(aptr[it] + k0);
      float4 ahi = *(const float4*)(aptr[it] + k0 + 4);
      uint4 av;
      av.x = pk2(alo.x, alo.y); av.y = pk2(alo.z, alo.w);
      av.z = pk2(ahi.x, ahi.y); av.w = pk2(ahi.z, ahi.w);
      As[slot_i[it]] = av;
      float4 blo = *(const float4*)(bptr[it] + k0);
      float4 bhi = *(const float4*)(bptr[it] + k0 + 4);
      uint4 bv;
      bv.x = pk2(blo.x, blo.y); bv.y = pk2(blo.z, blo.w);
      bv.z = pk2(bhi.x, bhi.y); bv.w = pk2(bhi.z, bhi.w);
      Bs[slot_i[it]] = bv;
    }
    __syncthreads();
#pragma unroll
    for (int kk = 0; kk < 2; ++kk) {
      const int ksr = lane >> 4;
      const int sw  = ((lane & 15) ^ (ksr << 1) ^ kk) + ksr * 16;
      bf16x8 af[4], bfr[4];
#pragma unroll
      for (int mi = 0; mi < 4; ++mi)
        af[mi] = ((const bf16x8*)As)[(kk * 8 + wr * 4 + mi) * 64 + sw];
#pragma unroll
      for (int ni = 0; ni < 4; ++ni)
        bfr[ni] = ((const bf16x8*)Bs)[(kk * 8 + wc * 4 + ni) * 64 + sw];
#pragma unroll
      for (int mi = 0; mi < 4; ++mi)
#pragma unroll
        for (int ni = 0; ni < 4; ++ni)
          acc[mi][ni] = __builtin_amdgcn_mfma_f32_16x16x32_bf16(
              af[mi], bfr[ni], acc[mi][ni], 0, 0, 0);
    }
  }

  const int col = lane & 15;
  const int r0  = (lane >> 4) * 4;
  float bvv[4];
#pragma unroll
  for (int ni = 0; ni < 4; ++ni)
    bvv[ni] = bias[lsel * EMBED + e0 + wc * 64 + ni * 16 + col];
#pragma unroll
  for (int mi = 0; mi < 4; ++mi) {
#pragma unroll
    for (int j = 0; j < 4; ++j) {
      const size_t ro = (size_t)rowsrc[wr * 64 + mi * 16 + r0 + j] * EMBED;
#pragma unroll
      for (int ni = 0; ni < 4; ++ni)
        out[ro + e0 + wc * 64 + ni * 16 + col] = acc[mi][ni][j] + bvv[ni];
    }
  }
}

extern "C" void kernel_launch(void* const* d_in, const int* in_sizes, int n_in,
                              void* d_out, int out_size, void* d_ws, size_t ws_size,
                              hipStream_t stream) {
  const float* feat = (const float*)d_in[0];
  const float* W    = (const float*)d_in[1];
  const float* bias = (const float*)d_in[2];
  const int*   toks = (const int*)d_in[3];
  float* out = (float*)d_out;

  const size_t wbf_bytes = (size_t)NLANG * EMBED * FEAT * 2;      // 16 MiB

  if (ws_size >= wbf_bytes) {
    ushort_t* Wbf = (ushort_t*)d_ws;
    convert_w_kernel<<<512, 256, 0, stream>>>(W, Wbf);
    (void)hipFuncSetAttribute((const void*)grouped_gemm_fused,
                              hipFuncAttributeMaxDynamicSharedMemorySize, 73728);
    const int nblk = (SEQ * BATCH / 128) * (EMBED / 256);         // 2048
    grouped_gemm_fused<<<nblk, 512, 73728, stream>>>(feat, Wbf, bias, toks, out);
  } else {
    grouped_proj_fused<<<(SEQ * BATCH / 128) * (EMBED / 128), 256, 0, stream>>>(
        feat, W, bias, toks, out);
  }
}